// Round 1
// baseline (1577.608 us; speedup 1.0000x reference)
//
#include <hip/hip_runtime.h>
#include <hip/hip_bf16.h>
#include <math.h>

#define BT 8192      // B*T rows total
#define TT 2048      // T
#define DM 1024      // d_model
#define DK 128       // dk == dv

// ---------------------------------------------------------------------------
// Projection GEMM: out[M][128] = X[M][1024] @ W[1024][128] + b
// grid.x = M/64 tiles, grid.y = {0:Q, 1:K, 2:V}
// BM=64, BN=128 (full), BK=32; 256 threads; 4x8 register tile per thread.
// ---------------------------------------------------------------------------
__global__ __launch_bounds__(256) void proj_kernel(
    const float* __restrict__ XQ, const float* __restrict__ XKV,
    const float* __restrict__ Wq, const float* __restrict__ bq,
    const float* __restrict__ Wk, const float* __restrict__ bk,
    const float* __restrict__ Wv, const float* __restrict__ bv,
    float* __restrict__ Qo, float* __restrict__ Ko, float* __restrict__ Vo)
{
    const int z = blockIdx.y;
    const float* __restrict__ X    = (z == 0) ? XQ : XKV;
    const float* __restrict__ W    = (z == 0) ? Wq : (z == 1 ? Wk : Wv);
    const float* __restrict__ bias = (z == 0) ? bq : (z == 1 ? bk : bv);
    float* __restrict__ out        = (z == 0) ? Qo : (z == 1 ? Ko : Vo);

    __shared__ float Xs[64][33];    // +1 pad breaks bank aliasing on row reads
    __shared__ float Ws[32][128];

    const int t  = threadIdx.x;
    const int tx = t & 15;          // col group: cols tx*8 .. tx*8+7
    const int ty = t >> 4;          // row group: rows ty*4 .. ty*4+3
    const int m0 = blockIdx.x * 64;

    float acc[4][8];
#pragma unroll
    for (int i = 0; i < 4; ++i)
#pragma unroll
        for (int j = 0; j < 8; ++j) acc[i][j] = 0.f;

    for (int k0 = 0; k0 < DM; k0 += 32) {
        // --- stage X tile: 64 x 32 floats (512 float4, 2 per thread) ---
#pragma unroll
        for (int jj = 0; jj < 2; ++jj) {
            int id  = t * 2 + jj;
            int row = id >> 3;
            int kc  = (id & 7) * 4;
            float4 v = *reinterpret_cast<const float4*>(
                &X[(size_t)(m0 + row) * DM + k0 + kc]);
            Xs[row][kc + 0] = v.x; Xs[row][kc + 1] = v.y;
            Xs[row][kc + 2] = v.z; Xs[row][kc + 3] = v.w;
        }
        // --- stage W tile: 32 x 128 floats (1024 float4, 4 per thread) ---
#pragma unroll
        for (int jj = 0; jj < 4; ++jj) {
            int id  = t * 4 + jj;
            int wk  = id >> 5;
            int col = (id & 31) * 4;
            *reinterpret_cast<float4*>(&Ws[wk][col]) =
                *reinterpret_cast<const float4*>(&W[(size_t)(k0 + wk) * DK + col]);
        }
        __syncthreads();

#pragma unroll 8
        for (int kk = 0; kk < 32; ++kk) {
            float a0 = Xs[ty * 4 + 0][kk];
            float a1 = Xs[ty * 4 + 1][kk];
            float a2 = Xs[ty * 4 + 2][kk];
            float a3 = Xs[ty * 4 + 3][kk];
            float4 b0 = *reinterpret_cast<const float4*>(&Ws[kk][tx * 8]);
            float4 b1 = *reinterpret_cast<const float4*>(&Ws[kk][tx * 8 + 4]);
            float bb[8] = {b0.x, b0.y, b0.z, b0.w, b1.x, b1.y, b1.z, b1.w};
            float aa[4] = {a0, a1, a2, a3};
#pragma unroll
            for (int i = 0; i < 4; ++i)
#pragma unroll
                for (int j = 0; j < 8; ++j)
                    acc[i][j] = fmaf(aa[i], bb[j], acc[i][j]);
        }
        __syncthreads();
    }

    // epilogue: add bias, store
#pragma unroll
    for (int i = 0; i < 4; ++i) {
        int row = m0 + ty * 4 + i;
        float4 r0, r1;
        r0.x = acc[i][0] + bias[tx * 8 + 0];
        r0.y = acc[i][1] + bias[tx * 8 + 1];
        r0.z = acc[i][2] + bias[tx * 8 + 2];
        r0.w = acc[i][3] + bias[tx * 8 + 3];
        r1.x = acc[i][4] + bias[tx * 8 + 4];
        r1.y = acc[i][5] + bias[tx * 8 + 5];
        r1.z = acc[i][6] + bias[tx * 8 + 6];
        r1.w = acc[i][7] + bias[tx * 8 + 7];
        *reinterpret_cast<float4*>(&out[(size_t)row * DK + tx * 8])     = r0;
        *reinterpret_cast<float4*>(&out[(size_t)row * DK + tx * 8 + 4]) = r1;
    }
}

// ---------------------------------------------------------------------------
// Causal flash attention, fp32. One wave (64 lanes) handles 4 query rows.
// Lane l owns dims {2l, 2l+1}. Online softmax; dot via shfl_xor butterfly.
// Block = 256 threads = 4 waves = 16 query rows. Grid = 8192/16 = 512 blocks.
// ---------------------------------------------------------------------------
__global__ __launch_bounds__(256) void attn_kernel(
    const float* __restrict__ Q, const float* __restrict__ K,
    const float* __restrict__ V, float* __restrict__ O)
{
    const int t    = threadIdx.x;
    const int lane = t & 63;
    const int wave = t >> 6;
    const int r0   = blockIdx.x * 16 + wave * 4;   // global row base (4 rows)
    const int b    = r0 / TT;
    const int q0   = r0 % TT;
    const float scale = 0.08838834764831845f;      // 1/sqrt(128)

    const float* __restrict__ Kb = K + (size_t)b * TT * DK;
    const float* __restrict__ Vb = V + (size_t)b * TT * DK;

    float2 q[4];
#pragma unroll
    for (int i = 0; i < 4; ++i)
        q[i] = *reinterpret_cast<const float2*>(&Q[(size_t)(r0 + i) * DK + 2 * lane]);

    float2 o[4];
    float  m[4], s[4];
#pragma unroll
    for (int i = 0; i < 4; ++i) {
        o[i] = make_float2(0.f, 0.f);
        m[i] = -1e30f;
        s[i] = 0.f;
    }

    const int kmax = q0 + 3;    // last key any of the 4 rows needs
    for (int k = 0; k <= kmax; ++k) {
        float2 kv = *reinterpret_cast<const float2*>(&Kb[(size_t)k * DK + 2 * lane]);
        float2 vv = *reinterpret_cast<const float2*>(&Vb[(size_t)k * DK + 2 * lane]);

        float p0 = q[0].x * kv.x + q[0].y * kv.y;
        float p1 = q[1].x * kv.x + q[1].y * kv.y;
        float p2 = q[2].x * kv.x + q[2].y * kv.y;
        float p3 = q[3].x * kv.x + q[3].y * kv.y;
#pragma unroll
        for (int off = 32; off > 0; off >>= 1) {
            p0 += __shfl_xor(p0, off);
            p1 += __shfl_xor(p1, off);
            p2 += __shfl_xor(p2, off);
            p3 += __shfl_xor(p3, off);
        }
        float sc[4] = {p0, p1, p2, p3};
#pragma unroll
        for (int i = 0; i < 4; ++i) {
            if (k <= q0 + i) {
                float x    = sc[i] * scale;
                float mn   = fmaxf(m[i], x);
                float corr = __expf(m[i] - mn);
                float p    = __expf(x - mn);
                s[i] = s[i] * corr + p;
                o[i].x = o[i].x * corr + p * vv.x;
                o[i].y = o[i].y * corr + p * vv.y;
                m[i] = mn;
            }
        }
    }

#pragma unroll
    for (int i = 0; i < 4; ++i) {
        float inv = 1.f / s[i];
        float2 r  = make_float2(o[i].x * inv, o[i].y * inv);
        *reinterpret_cast<float2*>(&O[(size_t)(r0 + i) * DK + 2 * lane]) = r;
    }
}

extern "C" void kernel_launch(void* const* d_in, const int* in_sizes, int n_in,
                              void* d_out, int out_size, void* d_ws, size_t ws_size,
                              hipStream_t stream) {
    const float* XQ  = (const float*)d_in[0];
    const float* XKV = (const float*)d_in[1];
    const float* Wq  = (const float*)d_in[2];
    const float* bq  = (const float*)d_in[3];
    const float* Wk  = (const float*)d_in[4];
    const float* bk  = (const float*)d_in[5];
    const float* Wv  = (const float*)d_in[6];
    const float* bv  = (const float*)d_in[7];

    float* Qo = (float*)d_ws;                       // 8192*128 fp32 = 4 MB
    float* Ko = Qo + (size_t)BT * DK;
    float* Vo = Ko + (size_t)BT * DK;               // total 12 MB of d_ws

    dim3 pgrid(BT / 64, 3);
    proj_kernel<<<pgrid, 256, 0, stream>>>(XQ, XKV, Wq, bq, Wk, bk, Wv, bv,
                                           Qo, Ko, Vo);

    attn_kernel<<<dim3(BT / 16), 256, 0, stream>>>(Qo, Ko, Vo, (float*)d_out);
}

// Round 2
// 233.270 us; speedup vs baseline: 6.7630x; 6.7630x over previous
//
#include <hip/hip_runtime.h>
#include <hip/hip_bf16.h>
#include <math.h>

#define BT 8192      // B*T rows total
#define TT 2048      // T
#define DM 1024      // d_model
#define DK 128       // dk == dv

typedef __bf16 bf16x8 __attribute__((ext_vector_type(8)));
typedef float  f32x4  __attribute__((ext_vector_type(4)));
typedef unsigned short ushort4v __attribute__((ext_vector_type(4)));
typedef unsigned short ushort8v __attribute__((ext_vector_type(8)));

static __device__ __forceinline__ unsigned short f2bf(float x) {
    union { float f; unsigned u; } v; v.f = x;
    unsigned r = v.u + 0x7fffu + ((v.u >> 16) & 1u);   // RNE
    return (unsigned short)(r >> 16);
}

// ---------------------------------------------------------------------------
// Projection GEMM (fp32 accum), outputs bf16: Qb[8192][128], Kb[8192][128],
// Vt[B=4][128][2048] (V transposed per batch for the PV MFMA A-operand).
// ---------------------------------------------------------------------------
__global__ __launch_bounds__(256) void proj_kernel(
    const float* __restrict__ XQ, const float* __restrict__ XKV,
    const float* __restrict__ Wq, const float* __restrict__ bq,
    const float* __restrict__ Wk, const float* __restrict__ bk,
    const float* __restrict__ Wv, const float* __restrict__ bv,
    unsigned short* __restrict__ Qb, unsigned short* __restrict__ Kb,
    unsigned short* __restrict__ Vt)
{
    const int z = blockIdx.y;
    const float* __restrict__ X    = (z == 0) ? XQ : XKV;
    const float* __restrict__ W    = (z == 0) ? Wq : (z == 1 ? Wk : Wv);
    const float* __restrict__ bias = (z == 0) ? bq : (z == 1 ? bk : bv);

    __shared__ float Xs[64][33];
    __shared__ float Ws[32][128];

    const int t  = threadIdx.x;
    const int tx = t & 15;          // cols tx*8 .. tx*8+7
    const int ty = t >> 4;          // rows ty*4 .. ty*4+3
    const int m0 = blockIdx.x * 64;

    float acc[4][8];
#pragma unroll
    for (int i = 0; i < 4; ++i)
#pragma unroll
        for (int j = 0; j < 8; ++j) acc[i][j] = 0.f;

    for (int k0 = 0; k0 < DM; k0 += 32) {
#pragma unroll
        for (int jj = 0; jj < 2; ++jj) {
            int id  = t * 2 + jj;
            int row = id >> 3;
            int kc  = (id & 7) * 4;
            float4 v = *reinterpret_cast<const float4*>(
                &X[(size_t)(m0 + row) * DM + k0 + kc]);
            Xs[row][kc + 0] = v.x; Xs[row][kc + 1] = v.y;
            Xs[row][kc + 2] = v.z; Xs[row][kc + 3] = v.w;
        }
#pragma unroll
        for (int jj = 0; jj < 4; ++jj) {
            int id  = t * 4 + jj;
            int wk  = id >> 5;
            int col = (id & 31) * 4;
            *reinterpret_cast<float4*>(&Ws[wk][col]) =
                *reinterpret_cast<const float4*>(&W[(size_t)(k0 + wk) * DK + col]);
        }
        __syncthreads();

#pragma unroll 8
        for (int kk = 0; kk < 32; ++kk) {
            float aa[4] = {Xs[ty * 4 + 0][kk], Xs[ty * 4 + 1][kk],
                           Xs[ty * 4 + 2][kk], Xs[ty * 4 + 3][kk]};
            float4 b0 = *reinterpret_cast<const float4*>(&Ws[kk][tx * 8]);
            float4 b1 = *reinterpret_cast<const float4*>(&Ws[kk][tx * 8 + 4]);
            float bb[8] = {b0.x, b0.y, b0.z, b0.w, b1.x, b1.y, b1.z, b1.w};
#pragma unroll
            for (int i = 0; i < 4; ++i)
#pragma unroll
                for (int j = 0; j < 8; ++j)
                    acc[i][j] = fmaf(aa[i], bb[j], acc[i][j]);
        }
        __syncthreads();
    }

    if (z < 2) {
        unsigned short* out = (z == 0) ? Qb : Kb;
#pragma unroll
        for (int i = 0; i < 4; ++i) {
            int row = m0 + ty * 4 + i;
            ushort8v r;
#pragma unroll
            for (int j = 0; j < 8; ++j)
                r[j] = f2bf(acc[i][j] + bias[tx * 8 + j]);
            *reinterpret_cast<ushort8v*>(&out[(size_t)row * DK + tx * 8]) = r;
        }
    } else {
        const int b  = m0 / TT;
        const int t0 = (m0 % TT) + ty * 4;
#pragma unroll
        for (int j = 0; j < 8; ++j) {
            int d = tx * 8 + j;
            ushort4v r;
#pragma unroll
            for (int i = 0; i < 4; ++i)
                r[i] = f2bf(acc[i][j] + bias[d]);
            *reinterpret_cast<ushort4v*>(&Vt[((size_t)b * DK + d) * TT + t0]) = r;
        }
    }
}

// ---------------------------------------------------------------------------
// MFMA flash attention. 1 wave = 16 query rows. Swapped QK^T: S^T = mfma(K,Q)
// so lane owns one q column (qi = lane&15); softmax per lane + 2 shfl_xor.
// P staged via padded LDS (stride 40 ushorts) to B-operand layout for PV.
// Vt gives contiguous 16B A-fragments for PV.  O^T C-layout -> float4 stores.
// ---------------------------------------------------------------------------
__global__ __launch_bounds__(64) void attn_kernel(
    const unsigned short* __restrict__ Qb, const unsigned short* __restrict__ Kb,
    const unsigned short* __restrict__ Vt, float* __restrict__ O)
{
    __shared__ __align__(16) unsigned short Plds[16][40];

    const int lane = threadIdx.x;
    const int qi   = lane & 15;
    const int g    = lane >> 4;

    // complement-pair remap for causal load balance
    const int nt   = gridDim.x;                       // 512
    const int bi   = blockIdx.x;
    const int tile = (bi & 1) ? (nt - 1 - (bi >> 1)) : (bi >> 1);

    const int r0 = tile * 16;                         // global row base
    const int b  = r0 / TT;
    const int q0 = r0 % TT;
    const int q  = q0 + qi;                           // this lane's query row
    const float scale = 0.08838834764831845f;         // 1/sqrt(128)

    const unsigned short* __restrict__ Kbb = Kb + (size_t)b * TT * DK;
    const unsigned short* __restrict__ Vtb = Vt + (size_t)b * DK * TT;

    bf16x8 qf[4];
#pragma unroll
    for (int c = 0; c < 4; ++c)
        qf[c] = *reinterpret_cast<const bf16x8*>(
            &Qb[(size_t)(r0 + qi) * DK + c * 32 + g * 8]);

    f32x4 accO[8];
#pragma unroll
    for (int dt = 0; dt < 8; ++dt) accO[dt] = (f32x4){0.f, 0.f, 0.f, 0.f};
    float m = -1e30f, s = 0.f;

    const int nsteps = (q0 + 16 + 31) >> 5;
    for (int st = 0; st < nsteps; ++st) {
        const int k0 = st * 32;

        f32x4 accS0 = (f32x4){0.f, 0.f, 0.f, 0.f};
        f32x4 accS1 = (f32x4){0.f, 0.f, 0.f, 0.f};
#pragma unroll
        for (int c = 0; c < 4; ++c) {
            bf16x8 kf0 = *reinterpret_cast<const bf16x8*>(
                &Kbb[(size_t)(k0 + qi) * DK + c * 32 + g * 8]);
            bf16x8 kf1 = *reinterpret_cast<const bf16x8*>(
                &Kbb[(size_t)(k0 + 16 + qi) * DK + c * 32 + g * 8]);
            accS0 = __builtin_amdgcn_mfma_f32_16x16x32_bf16(kf0, qf[c], accS0, 0, 0, 0);
            accS1 = __builtin_amdgcn_mfma_f32_16x16x32_bf16(kf1, qf[c], accS1, 0, 0, 0);
        }

        // ---- online softmax (lane owns q column; rows k = k0+sub*16+g*4+r)
        float x[8];
        float xmax = -1e30f;
#pragma unroll
        for (int sub = 0; sub < 2; ++sub)
#pragma unroll
            for (int r = 0; r < 4; ++r) {
                int k   = k0 + sub * 16 + g * 4 + r;
                float v = (sub ? accS1[r] : accS0[r]) * scale;
                v = (k <= q) ? v : -1e30f;
                x[sub * 4 + r] = v;
                xmax = fmaxf(xmax, v);
            }
        xmax = fmaxf(xmax, __shfl_xor(xmax, 16));
        xmax = fmaxf(xmax, __shfl_xor(xmax, 32));
        float mn   = fmaxf(m, xmax);
        float corr = __expf(m - mn);

        float ps = 0.f;
        ushort4v p0, p1;
#pragma unroll
        for (int i = 0; i < 8; ++i) {
            float p = __expf(x[i] - mn);
            ps += p;
            if (i < 4) p0[i] = f2bf(p); else p1[i - 4] = f2bf(p);
        }
        ps += __shfl_xor(ps, 16);
        ps += __shfl_xor(ps, 32);
        s = s * corr + ps;
        m = mn;

#pragma unroll
        for (int dt = 0; dt < 8; ++dt)
#pragma unroll
            for (int e = 0; e < 4; ++e) accO[dt][e] *= corr;

        // ---- P -> LDS (row qi, padded stride 40) then B-fragment read
        *reinterpret_cast<ushort4v*>(&Plds[qi][g * 4])      = p0;
        *reinterpret_cast<ushort4v*>(&Plds[qi][16 + g * 4]) = p1;
        bf16x8 pf = *reinterpret_cast<const bf16x8*>(&Plds[qi][g * 8]);

#pragma unroll
        for (int dt = 0; dt < 8; ++dt) {
            bf16x8 vf = *reinterpret_cast<const bf16x8*>(
                &Vtb[(size_t)(dt * 16 + qi) * TT + k0 + g * 8]);
            accO[dt] = __builtin_amdgcn_mfma_f32_16x16x32_bf16(vf, pf, accO[dt], 0, 0, 0);
        }
    }

    const float inv = 1.f / s;
#pragma unroll
    for (int dt = 0; dt < 8; ++dt) {
        float4 r;
        r.x = accO[dt][0] * inv; r.y = accO[dt][1] * inv;
        r.z = accO[dt][2] * inv; r.w = accO[dt][3] * inv;
        *reinterpret_cast<float4*>(&O[(size_t)(r0 + qi) * DK + dt * 16 + g * 4]) = r;
    }
}

extern "C" void kernel_launch(void* const* d_in, const int* in_sizes, int n_in,
                              void* d_out, int out_size, void* d_ws, size_t ws_size,
                              hipStream_t stream) {
    const float* XQ  = (const float*)d_in[0];
    const float* XKV = (const float*)d_in[1];
    const float* Wq  = (const float*)d_in[2];
    const float* bq  = (const float*)d_in[3];
    const float* Wk  = (const float*)d_in[4];
    const float* bk  = (const float*)d_in[5];
    const float* Wv  = (const float*)d_in[6];
    const float* bv  = (const float*)d_in[7];

    unsigned short* Qb = (unsigned short*)d_ws;                 // 2 MB
    unsigned short* Kb = Qb + (size_t)BT * DK;                  // 2 MB
    unsigned short* Vt = Kb + (size_t)BT * DK;                  // 2 MB

    dim3 pgrid(BT / 64, 3);
    proj_kernel<<<pgrid, 256, 0, stream>>>(XQ, XKV, Wq, bq, Wk, bk, Wv, bv,
                                           Qb, Kb, Vt);

    attn_kernel<<<dim3(BT / 16), 64, 0, stream>>>(Qb, Kb, Vt, (float*)d_out);
}

// Round 3
// 99.334 us; speedup vs baseline: 15.8819x; 2.3483x over previous
//
#include <hip/hip_runtime.h>
#include <hip/hip_bf16.h>
#include <math.h>

#define BT 8192      // B*T rows total
#define TT 2048      // T
#define DM 1024      // d_model
#define DK 128       // dk == dv

typedef __bf16 bf16x8 __attribute__((ext_vector_type(8)));
typedef float  f32x4  __attribute__((ext_vector_type(4)));
typedef unsigned short ushort4v __attribute__((ext_vector_type(4)));
typedef unsigned short ushort8v __attribute__((ext_vector_type(8)));

static __device__ __forceinline__ unsigned short f2bf(float x) {
    union { float f; unsigned u; } v; v.f = x;
    unsigned r = v.u + 0x7fffu + ((v.u >> 16) & 1u);   // RNE
    return (unsigned short)(r >> 16);
}

// ---------------------------------------------------------------------------
// Prep: Wt[z][n][k] = bf16(W_z[k][n]) — transposed weights for MFMA B-operand.
// grid (16 k-tiles, 3 z), 256 threads. LDS transpose, coalesced in and out.
// ---------------------------------------------------------------------------
__global__ __launch_bounds__(256) void wt_prep(
    const float* __restrict__ Wq, const float* __restrict__ Wk,
    const float* __restrict__ Wv, unsigned short* __restrict__ Wt)
{
    const int z = blockIdx.y;
    const float* __restrict__ W = (z == 0) ? Wq : (z == 1 ? Wk : Wv);
    const int k0 = blockIdx.x * 64;

    __shared__ __align__(16) __bf16 T[128][72];
    const int t = threadIdx.x;

#pragma unroll
    for (int jj = 0; jj < 8; ++jj) {
        int c  = jj * 256 + t;          // float4 chunk id, 2048 total
        int k  = c >> 5;                // 0..63
        int n4 = (c & 31) * 4;          // 0..124
        float4 f = *reinterpret_cast<const float4*>(&W[(size_t)(k0 + k) * DK + n4]);
        T[n4 + 0][k] = (__bf16)f.x;
        T[n4 + 1][k] = (__bf16)f.y;
        T[n4 + 2][k] = (__bf16)f.z;
        T[n4 + 3][k] = (__bf16)f.w;
    }
    __syncthreads();

    const int n  = t >> 1;
    const int cb = (t & 1) * 32;
#pragma unroll
    for (int jj = 0; jj < 4; ++jj) {
        *reinterpret_cast<ushort8v*>(&Wt[((size_t)z * DK + n) * DM + k0 + cb + jj * 8]) =
            *reinterpret_cast<const ushort8v*>(&T[n][cb + jj * 8]);
    }
}

// ---------------------------------------------------------------------------
// Projection via MFMA. out[m][n] = X[m][:]·W[:][n] + b.
// Tile: 64 rows x 128 cols, BK=64, 4 waves; wave w owns rows w*16..w*16+15.
// X fp32 -> bf16 reg-staged into LDS; Wt (bf16, pre-transposed) staged direct.
// mfma(xf, wf): C[row=g*4+r][col=i16] = Xrow(tile r)·Wtrow(col) — the exact
// operand/C mapping validated end-to-end by the round-2 attention kernel.
// ---------------------------------------------------------------------------
__global__ __launch_bounds__(256) void proj_mfma(
    const float* __restrict__ XQ, const float* __restrict__ XKV,
    const unsigned short* __restrict__ Wt,
    const float* __restrict__ bq, const float* __restrict__ bk,
    const float* __restrict__ bv,
    unsigned short* __restrict__ Qb, unsigned short* __restrict__ Kb,
    unsigned short* __restrict__ Vt)
{
    const int z = blockIdx.y;
    const float* __restrict__ X    = (z == 0) ? XQ : XKV;
    const float* __restrict__ bias = (z == 0) ? bq : (z == 1 ? bk : bv);
    const unsigned short* __restrict__ Wz = Wt + (size_t)z * DK * DM;

    __shared__ __align__(16) __bf16 Xl[64][72];
    __shared__ __align__(16) __bf16 Wl[128][72];

    const int t    = threadIdx.x;
    const int lane = t & 63;
    const int wv   = t >> 6;
    const int i16  = lane & 15;
    const int g    = lane >> 4;
    const int m0   = blockIdx.x * 64;

    f32x4 acc[8];
#pragma unroll
    for (int nt = 0; nt < 8; ++nt) acc[nt] = (f32x4){0.f, 0.f, 0.f, 0.f};

    for (int k0 = 0; k0 < DM; k0 += 64) {
        // stage X tile (64x64 fp32 -> bf16): thread t -> row t>>2, cols (t&3)*16..+16
        {
            int r  = t >> 2;
            int cb = (t & 3) * 16;
            const float4* src = reinterpret_cast<const float4*>(
                &X[(size_t)(m0 + r) * DM + k0 + cb]);
            float4 f0 = src[0], f1 = src[1], f2 = src[2], f3 = src[3];
            __bf16 tmp[16];
            tmp[0]  = (__bf16)f0.x; tmp[1]  = (__bf16)f0.y;
            tmp[2]  = (__bf16)f0.z; tmp[3]  = (__bf16)f0.w;
            tmp[4]  = (__bf16)f1.x; tmp[5]  = (__bf16)f1.y;
            tmp[6]  = (__bf16)f1.z; tmp[7]  = (__bf16)f1.w;
            tmp[8]  = (__bf16)f2.x; tmp[9]  = (__bf16)f2.y;
            tmp[10] = (__bf16)f2.z; tmp[11] = (__bf16)f2.w;
            tmp[12] = (__bf16)f3.x; tmp[13] = (__bf16)f3.y;
            tmp[14] = (__bf16)f3.z; tmp[15] = (__bf16)f3.w;
            *reinterpret_cast<bf16x8*>(&Xl[r][cb])     = *reinterpret_cast<bf16x8*>(&tmp[0]);
            *reinterpret_cast<bf16x8*>(&Xl[r][cb + 8]) = *reinterpret_cast<bf16x8*>(&tmp[8]);
        }
        // stage Wt tile (128x64 bf16): thread t -> row t>>1, cols (t&1)*32..+32
        {
            int n  = t >> 1;
            int cb = (t & 1) * 32;
            const ushort8v* src = reinterpret_cast<const ushort8v*>(
                &Wz[(size_t)n * DM + k0 + cb]);
            ushort8v w0 = src[0], w1 = src[1], w2 = src[2], w3 = src[3];
            *reinterpret_cast<ushort8v*>(&Wl[n][cb + 0])  = w0;
            *reinterpret_cast<ushort8v*>(&Wl[n][cb + 8])  = w1;
            *reinterpret_cast<ushort8v*>(&Wl[n][cb + 16]) = w2;
            *reinterpret_cast<ushort8v*>(&Wl[n][cb + 24]) = w3;
        }
        __syncthreads();

#pragma unroll
        for (int c = 0; c < 2; ++c) {
            bf16x8 xf = *reinterpret_cast<const bf16x8*>(&Xl[wv * 16 + i16][c * 32 + g * 8]);
#pragma unroll
            for (int nt = 0; nt < 8; ++nt) {
                bf16x8 wf = *reinterpret_cast<const bf16x8*>(&Wl[nt * 16 + i16][c * 32 + g * 8]);
                acc[nt] = __builtin_amdgcn_mfma_f32_16x16x32_bf16(xf, wf, acc[nt], 0, 0, 0);
            }
        }
        __syncthreads();
    }

    if (z < 2) {
        unsigned short* out = (z == 0) ? Qb : Kb;
#pragma unroll
        for (int nt = 0; nt < 8; ++nt) {
            int n = nt * 16 + i16;
            float bb = bias[n];
#pragma unroll
            for (int r = 0; r < 4; ++r) {
                int mrow = m0 + wv * 16 + g * 4 + r;
                out[(size_t)mrow * DK + n] = f2bf(acc[nt][r] + bb);
            }
        }
    } else {
        const int b  = m0 / TT;
        const int t0 = (m0 % TT) + wv * 16 + g * 4;
#pragma unroll
        for (int nt = 0; nt < 8; ++nt) {
            int d = nt * 16 + i16;
            float bb = bias[d];
            ushort4v r;
#pragma unroll
            for (int e = 0; e < 4; ++e) r[e] = f2bf(acc[nt][e] + bb);
            *reinterpret_cast<ushort4v*>(&Vt[((size_t)b * DK + d) * TT + t0]) = r;
        }
    }
}

// ---------------------------------------------------------------------------
// Split-K MFMA flash attention. Block = 4 waves, ONE 16-row q-tile.
// Wave w takes key-steps st = w, w+4, ... (32 keys each) with private online
// softmax (m, s, accO); partials combined in LDS at the end.
// ---------------------------------------------------------------------------
__global__ __launch_bounds__(256) void attn_kernel(
    const unsigned short* __restrict__ Qb, const unsigned short* __restrict__ Kb,
    const unsigned short* __restrict__ Vt, float* __restrict__ O)
{
    __shared__ __align__(16) unsigned short Plds[4][16][40];
    __shared__ __align__(16) float cacc[3][64][36];
    __shared__ float cm[4][16], cs[4][16];

    const int t    = threadIdx.x;
    const int lane = t & 63;
    const int w    = t >> 6;
    const int qi   = lane & 15;
    const int g    = lane >> 4;

    // complement-pair remap for causal load balance
    const int ntile = gridDim.x;                      // 512
    const int bi    = blockIdx.x;
    const int tile  = (bi & 1) ? (ntile - 1 - (bi >> 1)) : (bi >> 1);

    const int r0 = tile * 16;
    const int b  = r0 / TT;
    const int q0 = r0 % TT;
    const int q  = q0 + qi;
    const float scale = 0.08838834764831845f;         // 1/sqrt(128)

    const unsigned short* __restrict__ Kbb = Kb + (size_t)b * TT * DK;
    const unsigned short* __restrict__ Vtb = Vt + (size_t)b * DK * TT;

    bf16x8 qf[4];
#pragma unroll
    for (int c = 0; c < 4; ++c)
        qf[c] = *reinterpret_cast<const bf16x8*>(
            &Qb[(size_t)(r0 + qi) * DK + c * 32 + g * 8]);

    f32x4 accO[8];
#pragma unroll
    for (int dt = 0; dt < 8; ++dt) accO[dt] = (f32x4){0.f, 0.f, 0.f, 0.f};
    float m = -1e30f, s = 0.f;

    const int nsteps = (q0 + 16 + 31) >> 5;
    for (int st = w; st < nsteps; st += 4) {
        const int k0 = st * 32;

        f32x4 accS0 = (f32x4){0.f, 0.f, 0.f, 0.f};
        f32x4 accS1 = (f32x4){0.f, 0.f, 0.f, 0.f};
#pragma unroll
        for (int c = 0; c < 4; ++c) {
            bf16x8 kf0 = *reinterpret_cast<const bf16x8*>(
                &Kbb[(size_t)(k0 + qi) * DK + c * 32 + g * 8]);
            bf16x8 kf1 = *reinterpret_cast<const bf16x8*>(
                &Kbb[(size_t)(k0 + 16 + qi) * DK + c * 32 + g * 8]);
            accS0 = __builtin_amdgcn_mfma_f32_16x16x32_bf16(kf0, qf[c], accS0, 0, 0, 0);
            accS1 = __builtin_amdgcn_mfma_f32_16x16x32_bf16(kf1, qf[c], accS1, 0, 0, 0);
        }

        float x[8];
        float xmax = -1e30f;
#pragma unroll
        for (int sub = 0; sub < 2; ++sub)
#pragma unroll
            for (int r = 0; r < 4; ++r) {
                int k   = k0 + sub * 16 + g * 4 + r;
                float v = (sub ? accS1[r] : accS0[r]) * scale;
                v = (k <= q) ? v : -1e30f;
                x[sub * 4 + r] = v;
                xmax = fmaxf(xmax, v);
            }
        xmax = fmaxf(xmax, __shfl_xor(xmax, 16));
        xmax = fmaxf(xmax, __shfl_xor(xmax, 32));
        float mn   = fmaxf(m, xmax);
        float corr = __expf(m - mn);

        float ps = 0.f;
        ushort4v p0, p1;
#pragma unroll
        for (int i = 0; i < 8; ++i) {
            float p = __expf(x[i] - mn);
            ps += p;
            if (i < 4) p0[i] = f2bf(p); else p1[i - 4] = f2bf(p);
        }
        ps += __shfl_xor(ps, 16);
        ps += __shfl_xor(ps, 32);
        s = s * corr + ps;
        m = mn;

#pragma unroll
        for (int dt = 0; dt < 8; ++dt)
#pragma unroll
            for (int e = 0; e < 4; ++e) accO[dt][e] *= corr;

        *reinterpret_cast<ushort4v*>(&Plds[w][qi][g * 4])      = p0;
        *reinterpret_cast<ushort4v*>(&Plds[w][qi][16 + g * 4]) = p1;
        bf16x8 pf = *reinterpret_cast<const bf16x8*>(&Plds[w][qi][g * 8]);

#pragma unroll
        for (int dt = 0; dt < 8; ++dt) {
            bf16x8 vf = *reinterpret_cast<const bf16x8*>(
                &Vtb[(size_t)(dt * 16 + qi) * TT + k0 + g * 8]);
            accO[dt] = __builtin_amdgcn_mfma_f32_16x16x32_bf16(vf, pf, accO[dt], 0, 0, 0);
        }
    }

    // ---- combine partials across the 4 waves
    if (g == 0) { cm[w][qi] = m; cs[w][qi] = s; }
    __syncthreads();

    float mstar = fmaxf(fmaxf(cm[0][qi], cm[1][qi]), fmaxf(cm[2][qi], cm[3][qi]));
    float cw = __expf(m - mstar);

    if (w != 0) {
#pragma unroll
        for (int dt = 0; dt < 8; ++dt) {
            f32x4 v;
#pragma unroll
            for (int e = 0; e < 4; ++e) v[e] = accO[dt][e] * cw;
            *reinterpret_cast<f32x4*>(&cacc[w - 1][lane][dt * 4]) = v;
        }
    } else {
#pragma unroll
        for (int dt = 0; dt < 8; ++dt)
#pragma unroll
            for (int e = 0; e < 4; ++e) accO[dt][e] *= cw;
    }
    __syncthreads();

    if (w == 0) {
        float sstar = 0.f;
#pragma unroll
        for (int ww = 0; ww < 4; ++ww)
            sstar += cs[ww][qi] * __expf(cm[ww][qi] - mstar);

#pragma unroll
        for (int ww = 0; ww < 3; ++ww)
#pragma unroll
            for (int dt = 0; dt < 8; ++dt) {
                f32x4 v = *reinterpret_cast<const f32x4*>(&cacc[ww][lane][dt * 4]);
#pragma unroll
                for (int e = 0; e < 4; ++e) accO[dt][e] += v[e];
            }

        const float inv = 1.f / sstar;
#pragma unroll
        for (int dt = 0; dt < 8; ++dt) {
            float4 r;
            r.x = accO[dt][0] * inv; r.y = accO[dt][1] * inv;
            r.z = accO[dt][2] * inv; r.w = accO[dt][3] * inv;
            *reinterpret_cast<float4*>(&O[(size_t)(r0 + qi) * DK + dt * 16 + g * 4]) = r;
        }
    }
}

extern "C" void kernel_launch(void* const* d_in, const int* in_sizes, int n_in,
                              void* d_out, int out_size, void* d_ws, size_t ws_size,
                              hipStream_t stream) {
    const float* XQ  = (const float*)d_in[0];
    const float* XKV = (const float*)d_in[1];
    const float* Wq  = (const float*)d_in[2];
    const float* bq  = (const float*)d_in[3];
    const float* Wk  = (const float*)d_in[4];
    const float* bk  = (const float*)d_in[5];
    const float* Wv  = (const float*)d_in[6];
    const float* bv  = (const float*)d_in[7];

    unsigned short* Qb = (unsigned short*)d_ws;                 // 2 MB
    unsigned short* Kb = Qb + (size_t)BT * DK;                  // 2 MB
    unsigned short* Vt = Kb + (size_t)BT * DK;                  // 2 MB
    unsigned short* Wt = Vt + (size_t)BT * DK;                  // 0.75 MB

    wt_prep<<<dim3(16, 3), 256, 0, stream>>>(Wq, Wk, Wv, Wt);

    proj_mfma<<<dim3(BT / 64, 3), 256, 0, stream>>>(
        XQ, XKV, Wt, bq, bk, bv, Qb, Kb, Vt);

    attn_kernel<<<dim3(BT / 16), 256, 0, stream>>>(Qb, Kb, Vt, (float*)d_out);
}

// Round 4
// 99.139 us; speedup vs baseline: 15.9131x; 1.0020x over previous
//
#include <hip/hip_runtime.h>
#include <hip/hip_bf16.h>
#include <math.h>

#define BT 8192      // B*T rows total
#define TT 2048      // T
#define DM 1024      // d_model
#define DK 128       // dk == dv

typedef __bf16 bf16x4 __attribute__((ext_vector_type(4)));
typedef __bf16 bf16x8 __attribute__((ext_vector_type(8)));
typedef float  f32x4  __attribute__((ext_vector_type(4)));
typedef unsigned short ushort4v __attribute__((ext_vector_type(4)));
typedef unsigned short ushort8v __attribute__((ext_vector_type(8)));

static __device__ __forceinline__ unsigned short f2bf(float x) {
    union { float f; unsigned u; } v; v.f = x;
    unsigned r = v.u + 0x7fffu + ((v.u >> 16) & 1u);   // RNE
    return (unsigned short)(r >> 16);
}

// 1/sqrt(128) * log2(e): QK^T computed directly in log2 domain
#define QSCALE 0.1275312772629451f

// ---------------------------------------------------------------------------
// Prep: Wt[z][n][k] = bf16(W_z[k][n]) — transposed weights for MFMA B-operand.
// ---------------------------------------------------------------------------
__global__ __launch_bounds__(256) void wt_prep(
    const float* __restrict__ Wq, const float* __restrict__ Wk,
    const float* __restrict__ Wv, unsigned short* __restrict__ Wt)
{
    const int z = blockIdx.y;
    const float* __restrict__ W = (z == 0) ? Wq : (z == 1 ? Wk : Wv);
    const int k0 = blockIdx.x * 64;

    __shared__ __align__(16) __bf16 T[128][72];
    const int t = threadIdx.x;

#pragma unroll
    for (int jj = 0; jj < 8; ++jj) {
        int c  = jj * 256 + t;
        int k  = c >> 5;
        int n4 = (c & 31) * 4;
        float4 f = *reinterpret_cast<const float4*>(&W[(size_t)(k0 + k) * DK + n4]);
        T[n4 + 0][k] = (__bf16)f.x;
        T[n4 + 1][k] = (__bf16)f.y;
        T[n4 + 2][k] = (__bf16)f.z;
        T[n4 + 3][k] = (__bf16)f.w;
    }
    __syncthreads();

    const int n  = t >> 1;
    const int cb = (t & 1) * 32;
#pragma unroll
    for (int jj = 0; jj < 4; ++jj) {
        *reinterpret_cast<ushort8v*>(&Wt[((size_t)z * DK + n) * DM + k0 + cb + jj * 8]) =
            *reinterpret_cast<const ushort8v*>(&T[n][cb + jj * 8]);
    }
}

// ---------------------------------------------------------------------------
// Projection via MFMA. Tile 64x128, BK=64, 4 waves.
// z==0 epilogue folds QSCALE into Q (attention runs in exp2 domain).
// ---------------------------------------------------------------------------
__global__ __launch_bounds__(256) void proj_mfma(
    const float* __restrict__ XQ, const float* __restrict__ XKV,
    const unsigned short* __restrict__ Wt,
    const float* __restrict__ bq, const float* __restrict__ bk,
    const float* __restrict__ bv,
    unsigned short* __restrict__ Qb, unsigned short* __restrict__ Kb,
    unsigned short* __restrict__ Vt)
{
    const int z = blockIdx.y;
    const float* __restrict__ X    = (z == 0) ? XQ : XKV;
    const float* __restrict__ bias = (z == 0) ? bq : (z == 1 ? bk : bv);
    const unsigned short* __restrict__ Wz = Wt + (size_t)z * DK * DM;

    __shared__ __align__(16) __bf16 Xl[64][72];
    __shared__ __align__(16) __bf16 Wl[128][72];

    const int t    = threadIdx.x;
    const int lane = t & 63;
    const int wv   = t >> 6;
    const int i16  = lane & 15;
    const int g    = lane >> 4;
    const int m0   = blockIdx.x * 64;

    f32x4 acc[8];
#pragma unroll
    for (int nt = 0; nt < 8; ++nt) acc[nt] = (f32x4){0.f, 0.f, 0.f, 0.f};

    for (int k0 = 0; k0 < DM; k0 += 64) {
        {
            int r  = t >> 2;
            int cb = (t & 3) * 16;
            const float4* src = reinterpret_cast<const float4*>(
                &X[(size_t)(m0 + r) * DM + k0 + cb]);
            float4 f0 = src[0], f1 = src[1], f2 = src[2], f3 = src[3];
            __bf16 tmp[16];
            tmp[0]  = (__bf16)f0.x; tmp[1]  = (__bf16)f0.y;
            tmp[2]  = (__bf16)f0.z; tmp[3]  = (__bf16)f0.w;
            tmp[4]  = (__bf16)f1.x; tmp[5]  = (__bf16)f1.y;
            tmp[6]  = (__bf16)f1.z; tmp[7]  = (__bf16)f1.w;
            tmp[8]  = (__bf16)f2.x; tmp[9]  = (__bf16)f2.y;
            tmp[10] = (__bf16)f2.z; tmp[11] = (__bf16)f2.w;
            tmp[12] = (__bf16)f3.x; tmp[13] = (__bf16)f3.y;
            tmp[14] = (__bf16)f3.z; tmp[15] = (__bf16)f3.w;
            *reinterpret_cast<bf16x8*>(&Xl[r][cb])     = *reinterpret_cast<bf16x8*>(&tmp[0]);
            *reinterpret_cast<bf16x8*>(&Xl[r][cb + 8]) = *reinterpret_cast<bf16x8*>(&tmp[8]);
        }
        {
            int n  = t >> 1;
            int cb = (t & 1) * 32;
            const ushort8v* src = reinterpret_cast<const ushort8v*>(
                &Wz[(size_t)n * DM + k0 + cb]);
            ushort8v w0 = src[0], w1 = src[1], w2 = src[2], w3 = src[3];
            *reinterpret_cast<ushort8v*>(&Wl[n][cb + 0])  = w0;
            *reinterpret_cast<ushort8v*>(&Wl[n][cb + 8])  = w1;
            *reinterpret_cast<ushort8v*>(&Wl[n][cb + 16]) = w2;
            *reinterpret_cast<ushort8v*>(&Wl[n][cb + 24]) = w3;
        }
        __syncthreads();

#pragma unroll
        for (int c = 0; c < 2; ++c) {
            bf16x8 xf = *reinterpret_cast<const bf16x8*>(&Xl[wv * 16 + i16][c * 32 + g * 8]);
#pragma unroll
            for (int nt = 0; nt < 8; ++nt) {
                bf16x8 wf = *reinterpret_cast<const bf16x8*>(&Wl[nt * 16 + i16][c * 32 + g * 8]);
                acc[nt] = __builtin_amdgcn_mfma_f32_16x16x32_bf16(xf, wf, acc[nt], 0, 0, 0);
            }
        }
        __syncthreads();
    }

    if (z == 0) {
#pragma unroll
        for (int nt = 0; nt < 8; ++nt) {
            int n = nt * 16 + i16;
            float bb = bias[n];
#pragma unroll
            for (int r = 0; r < 4; ++r) {
                int mrow = m0 + wv * 16 + g * 4 + r;
                Qb[(size_t)mrow * DK + n] = f2bf((acc[nt][r] + bb) * QSCALE);
            }
        }
    } else if (z == 1) {
#pragma unroll
        for (int nt = 0; nt < 8; ++nt) {
            int n = nt * 16 + i16;
            float bb = bias[n];
#pragma unroll
            for (int r = 0; r < 4; ++r) {
                int mrow = m0 + wv * 16 + g * 4 + r;
                Kb[(size_t)mrow * DK + n] = f2bf(acc[nt][r] + bb);
            }
        }
    } else {
        const int b  = m0 / TT;
        const int t0 = (m0 % TT) + wv * 16 + g * 4;
#pragma unroll
        for (int nt = 0; nt < 8; ++nt) {
            int d = nt * 16 + i16;
            float bb = bias[d];
            ushort4v r;
#pragma unroll
            for (int e = 0; e < 4; ++e) r[e] = f2bf(acc[nt][e] + bb);
            *reinterpret_cast<ushort4v*>(&Vt[((size_t)b * DK + d) * TT + t0]) = r;
        }
    }
}

// ---------------------------------------------------------------------------
// Split-K x8 MFMA flash attention, exp2 domain, defer-max.
// Block = 8 waves, one 16-row q-tile; wave w takes steps st = w, w+8, ...
// Tree combine (3 rounds) through 4 LDS slots. XCD-aware balanced tile remap.
// ---------------------------------------------------------------------------
__global__ __launch_bounds__(512, 4) void attn_kernel(
    const unsigned short* __restrict__ Qb, const unsigned short* __restrict__ Kb,
    const unsigned short* __restrict__ Vt, float* __restrict__ O)
{
    __shared__ __align__(16) unsigned short Plds[8][16][40];
    __shared__ __align__(16) float slot[4][64][36];
    __shared__ float cm[8][16], cs[8][16];

    const int t    = threadIdx.x;
    const int lane = t & 63;
    const int w    = t >> 6;
    const int qi   = lane & 15;
    const int g    = lane >> 4;

    // XCD-aware balanced remap: within each XCD stream (bi&7 fixed),
    // consecutive block pairs are (light j, heavy 511-j) -> constant work.
    const int bi = blockIdx.x;
    const int x8v = bi & 7;
    const int u   = bi >> 3;          // 0..63 within XCD stream
    const int v   = u >> 1;
    const int j   = v * 8 + x8v;      // 0..255
    const int tile = (u & 1) ? (511 - j) : j;

    const int r0 = tile * 16;
    const int b  = r0 / TT;
    const int q0 = r0 % TT;
    const int q  = q0 + qi;

    const unsigned short* __restrict__ Kbb = Kb + (size_t)b * TT * DK;
    const unsigned short* __restrict__ Vtb = Vt + (size_t)b * DK * TT;

    bf16x8 qf[4];
#pragma unroll
    for (int c = 0; c < 4; ++c)
        qf[c] = *reinterpret_cast<const bf16x8*>(
            &Qb[(size_t)(r0 + qi) * DK + c * 32 + g * 8]);

    f32x4 accO[8];
#pragma unroll
    for (int dt = 0; dt < 8; ++dt) accO[dt] = (f32x4){0.f, 0.f, 0.f, 0.f};
    float m = -1e30f, s = 0.f;        // s is LANE-LOCAL (summed across g at end)

    const int nsteps = (q0 + 16 + 31) >> 5;
    for (int st = w; st < nsteps; st += 8) {
        const int k0 = st * 32;

        f32x4 accS0 = (f32x4){0.f, 0.f, 0.f, 0.f};
        f32x4 accS1 = (f32x4){0.f, 0.f, 0.f, 0.f};
#pragma unroll
        for (int c = 0; c < 4; ++c) {
            bf16x8 kf0 = *reinterpret_cast<const bf16x8*>(
                &Kbb[(size_t)(k0 + qi) * DK + c * 32 + g * 8]);
            bf16x8 kf1 = *reinterpret_cast<const bf16x8*>(
                &Kbb[(size_t)(k0 + 16 + qi) * DK + c * 32 + g * 8]);
            accS0 = __builtin_amdgcn_mfma_f32_16x16x32_bf16(kf0, qf[c], accS0, 0, 0, 0);
            accS1 = __builtin_amdgcn_mfma_f32_16x16x32_bf16(kf1, qf[c], accS1, 0, 0, 0);
        }

        // scores already in log2 domain (QSCALE folded into Q)
        float xs[8];
        float xmax = -1e30f;
        if (st == nsteps - 1) {       // only boundary step needs the causal mask
#pragma unroll
            for (int sub = 0; sub < 2; ++sub)
#pragma unroll
                for (int r = 0; r < 4; ++r) {
                    int k   = k0 + sub * 16 + g * 4 + r;
                    float v0 = (sub ? accS1[r] : accS0[r]);
                    v0 = (k <= q) ? v0 : -1e30f;
                    xs[sub * 4 + r] = v0;
                    xmax = fmaxf(xmax, v0);
                }
        } else {
#pragma unroll
            for (int sub = 0; sub < 2; ++sub)
#pragma unroll
                for (int r = 0; r < 4; ++r) {
                    float v0 = (sub ? accS1[r] : accS0[r]);
                    xs[sub * 4 + r] = v0;
                    xmax = fmaxf(xmax, v0);
                }
        }

        // defer-max: only rescale when the running max actually grows by >8
        if (__any(xmax > m + 8.f)) {
            xmax = fmaxf(xmax, __shfl_xor(xmax, 16));
            xmax = fmaxf(xmax, __shfl_xor(xmax, 32));
            float mn   = fmaxf(m, xmax);
            float corr = __builtin_amdgcn_exp2f(m - mn);
            s *= corr;
#pragma unroll
            for (int dt = 0; dt < 8; ++dt)
#pragma unroll
                for (int e = 0; e < 4; ++e) accO[dt][e] *= corr;
            m = mn;
        }

        __bf16 pb[8];
#pragma unroll
        for (int i = 0; i < 8; ++i) {
            float p = __builtin_amdgcn_exp2f(xs[i] - m);
            s += p;
            pb[i] = (__bf16)p;
        }

        *reinterpret_cast<bf16x4*>(&Plds[w][qi][g * 4])      = *reinterpret_cast<bf16x4*>(&pb[0]);
        *reinterpret_cast<bf16x4*>(&Plds[w][qi][16 + g * 4]) = *reinterpret_cast<bf16x4*>(&pb[4]);
        bf16x8 pf = *reinterpret_cast<const bf16x8*>(&Plds[w][qi][g * 8]);

#pragma unroll
        for (int dt = 0; dt < 8; ++dt) {
            bf16x8 vf = *reinterpret_cast<const bf16x8*>(
                &Vtb[(size_t)(dt * 16 + qi) * TT + k0 + g * 8]);
            accO[dt] = __builtin_amdgcn_mfma_f32_16x16x32_bf16(vf, pf, accO[dt], 0, 0, 0);
        }
    }

    // ---- combine the 8 wave-partials ----
    float srow = s + __shfl_xor(s, 16);
    srow += __shfl_xor(srow, 32);
    if (g == 0) { cm[w][qi] = m; cs[w][qi] = srow; }
    __syncthreads();

    float mstar = cm[0][qi];
#pragma unroll
    for (int ww = 1; ww < 8; ++ww) mstar = fmaxf(mstar, cm[ww][qi]);
    float sstar = 0.f;
#pragma unroll
    for (int ww = 0; ww < 8; ++ww)
        sstar += cs[ww][qi] * __builtin_amdgcn_exp2f(cm[ww][qi] - mstar);

    float cw = __builtin_amdgcn_exp2f(m - mstar);
#pragma unroll
    for (int dt = 0; dt < 8; ++dt)
#pragma unroll
        for (int e = 0; e < 4; ++e) accO[dt][e] *= cw;

    // tree round 1: odd waves -> slots 0..3
    if (w & 1)
#pragma unroll
        for (int dt = 0; dt < 8; ++dt)
            *reinterpret_cast<f32x4*>(&slot[w >> 1][lane][dt * 4]) = accO[dt];
    __syncthreads();
    if (!(w & 1))
#pragma unroll
        for (int dt = 0; dt < 8; ++dt) {
            f32x4 v0 = *reinterpret_cast<const f32x4*>(&slot[w >> 1][lane][dt * 4]);
#pragma unroll
            for (int e = 0; e < 4; ++e) accO[dt][e] += v0[e];
        }
    __syncthreads();
    // round 2: waves 2,6 -> slots 0,1
    if (!(w & 1) && (w & 2))
#pragma unroll
        for (int dt = 0; dt < 8; ++dt)
            *reinterpret_cast<f32x4*>(&slot[w >> 2][lane][dt * 4]) = accO[dt];
    __syncthreads();
    if ((w & 3) == 0)
#pragma unroll
        for (int dt = 0; dt < 8; ++dt) {
            f32x4 v0 = *reinterpret_cast<const f32x4*>(&slot[w >> 2][lane][dt * 4]);
#pragma unroll
            for (int e = 0; e < 4; ++e) accO[dt][e] += v0[e];
        }
    __syncthreads();
    // round 3: wave 4 -> slot 0
    if (w == 4)
#pragma unroll
        for (int dt = 0; dt < 8; ++dt)
            *reinterpret_cast<f32x4*>(&slot[0][lane][dt * 4]) = accO[dt];
    __syncthreads();

    if (w == 0) {
        const float inv = 1.f / sstar;
#pragma unroll
        for (int dt = 0; dt < 8; ++dt) {
            f32x4 v0 = *reinterpret_cast<const f32x4*>(&slot[0][lane][dt * 4]);
            float4 r;
            r.x = (accO[dt][0] + v0[0]) * inv;
            r.y = (accO[dt][1] + v0[1]) * inv;
            r.z = (accO[dt][2] + v0[2]) * inv;
            r.w = (accO[dt][3] + v0[3]) * inv;
            *reinterpret_cast<float4*>(&O[(size_t)(r0 + qi) * DK + dt * 16 + g * 4]) = r;
        }
    }
}

extern "C" void kernel_launch(void* const* d_in, const int* in_sizes, int n_in,
                              void* d_out, int out_size, void* d_ws, size_t ws_size,
                              hipStream_t stream) {
    const float* XQ  = (const float*)d_in[0];
    const float* XKV = (const float*)d_in[1];
    const float* Wq  = (const float*)d_in[2];
    const float* bq  = (const float*)d_in[3];
    const float* Wk  = (const float*)d_in[4];
    const float* bk  = (const float*)d_in[5];
    const float* Wv  = (const float*)d_in[6];
    const float* bv  = (const float*)d_in[7];

    unsigned short* Qb = (unsigned short*)d_ws;                 // 2 MB
    unsigned short* Kb = Qb + (size_t)BT * DK;                  // 2 MB
    unsigned short* Vt = Kb + (size_t)BT * DK;                  // 2 MB
    unsigned short* Wt = Vt + (size_t)BT * DK;                  // 0.75 MB

    wt_prep<<<dim3(16, 3), 256, 0, stream>>>(Wq, Wk, Wv, Wt);

    proj_mfma<<<dim3(BT / 64, 3), 256, 0, stream>>>(
        XQ, XKV, Wt, bq, bk, bv, Qb, Kb, Vt);

    attn_kernel<<<dim3(BT / 16), 512, 0, stream>>>(Qb, Kb, Vt, (float*)d_out);
}

// Round 6
// 65.863 us; speedup vs baseline: 23.9530x; 1.5052x over previous
//
#include <hip/hip_runtime.h>
#include <hip/hip_bf16.h>
#include <math.h>

#define BT 8192      // B*T rows total
#define TT 2048      // T
#define DM 1024      // d_model
#define DK 128       // dk == dv
#define NBLK 65      // split-K blocks per batch (sum of S over 16 q-blocks)

typedef __bf16 bf16x8 __attribute__((ext_vector_type(8)));
typedef float  f32x4  __attribute__((ext_vector_type(4)));
typedef unsigned short ushort4v __attribute__((ext_vector_type(4)));
typedef unsigned short ushort8v __attribute__((ext_vector_type(8)));

static __device__ __forceinline__ unsigned short f2bf(float x) {
    union { float f; unsigned u; } v; v.f = x;
    unsigned r = v.u + 0x7fffu + ((v.u >> 16) & 1u);   // RNE
    return (unsigned short)(r >> 16);
}
static __device__ __forceinline__ float bf2f(unsigned short u) {
    union { unsigned u; float f; } v; v.u = (unsigned)u << 16;
    return v.f;
}

// slices for q-block index q (0..15):  S = max(1, (q+1)>>1)   (sum = 65)
// prefix:  pfx(q) = 0 (q==0) else 1 + (q*q - (q&1))/4
__host__ __device__ constexpr int slc_of(int q) { return (q == 0) ? 1 : ((q + 1) >> 1); }
__host__ __device__ constexpr int pfx_of(int q) { return (q == 0) ? 0 : 1 + (q * q - (q & 1)) / 4; }

// 1/sqrt(128) * log2(e): QK^T computed directly in log2 domain
#define QSCALE 0.1275312772629451f

// ---------------------------------------------------------------------------
// Prep: Wt[z][n][k] = bf16(W_z[k][n])
// ---------------------------------------------------------------------------
__global__ __launch_bounds__(256) void wt_prep(
    const float* __restrict__ Wq, const float* __restrict__ Wk,
    const float* __restrict__ Wv, unsigned short* __restrict__ Wt)
{
    const int z = blockIdx.y;
    const float* __restrict__ W = (z == 0) ? Wq : (z == 1 ? Wk : Wv);
    const int k0 = blockIdx.x * 64;

    __shared__ __align__(16) __bf16 T[128][72];
    const int t = threadIdx.x;

#pragma unroll
    for (int jj = 0; jj < 8; ++jj) {
        int c  = jj * 256 + t;
        int k  = c >> 5;
        int n4 = (c & 31) * 4;
        float4 f = *reinterpret_cast<const float4*>(&W[(size_t)(k0 + k) * DK + n4]);
        T[n4 + 0][k] = (__bf16)f.x;
        T[n4 + 1][k] = (__bf16)f.y;
        T[n4 + 2][k] = (__bf16)f.z;
        T[n4 + 3][k] = (__bf16)f.w;
    }
    __syncthreads();

    const int n  = t >> 1;
    const int cb = (t & 1) * 32;
#pragma unroll
    for (int jj = 0; jj < 4; ++jj) {
        *reinterpret_cast<ushort8v*>(&Wt[((size_t)z * DK + n) * DM + k0 + cb + jj * 8]) =
            *reinterpret_cast<const ushort8v*>(&T[n][cb + jj * 8]);
    }
}

// ---------------------------------------------------------------------------
// Projection via MFMA (Q pre-scaled by QSCALE).
// ---------------------------------------------------------------------------
__global__ __launch_bounds__(256) void proj_mfma(
    const float* __restrict__ XQ, const float* __restrict__ XKV,
    const unsigned short* __restrict__ Wt,
    const float* __restrict__ bq, const float* __restrict__ bk,
    const float* __restrict__ bv,
    unsigned short* __restrict__ Qb, unsigned short* __restrict__ Kb,
    unsigned short* __restrict__ Vt)
{
    const int z = blockIdx.y;
    const float* __restrict__ X    = (z == 0) ? XQ : XKV;
    const float* __restrict__ bias = (z == 0) ? bq : (z == 1 ? bk : bv);
    const unsigned short* __restrict__ Wz = Wt + (size_t)z * DK * DM;

    __shared__ __align__(16) __bf16 Xl[64][72];
    __shared__ __align__(16) __bf16 Wl[128][72];

    const int t    = threadIdx.x;
    const int lane = t & 63;
    const int wv   = t >> 6;
    const int i16  = lane & 15;
    const int g    = lane >> 4;
    const int m0   = blockIdx.x * 64;

    f32x4 acc[8];
#pragma unroll
    for (int nt = 0; nt < 8; ++nt) acc[nt] = (f32x4){0.f, 0.f, 0.f, 0.f};

    for (int k0 = 0; k0 < DM; k0 += 64) {
        {
            int r  = t >> 2;
            int cb = (t & 3) * 16;
            const float4* src = reinterpret_cast<const float4*>(
                &X[(size_t)(m0 + r) * DM + k0 + cb]);
            float4 f0 = src[0], f1 = src[1], f2 = src[2], f3 = src[3];
            __bf16 tmp[16];
            tmp[0]  = (__bf16)f0.x; tmp[1]  = (__bf16)f0.y;
            tmp[2]  = (__bf16)f0.z; tmp[3]  = (__bf16)f0.w;
            tmp[4]  = (__bf16)f1.x; tmp[5]  = (__bf16)f1.y;
            tmp[6]  = (__bf16)f1.z; tmp[7]  = (__bf16)f1.w;
            tmp[8]  = (__bf16)f2.x; tmp[9]  = (__bf16)f2.y;
            tmp[10] = (__bf16)f2.z; tmp[11] = (__bf16)f2.w;
            tmp[12] = (__bf16)f3.x; tmp[13] = (__bf16)f3.y;
            tmp[14] = (__bf16)f3.z; tmp[15] = (__bf16)f3.w;
            *reinterpret_cast<bf16x8*>(&Xl[r][cb])     = *reinterpret_cast<bf16x8*>(&tmp[0]);
            *reinterpret_cast<bf16x8*>(&Xl[r][cb + 8]) = *reinterpret_cast<bf16x8*>(&tmp[8]);
        }
        {
            int n  = t >> 1;
            int cb = (t & 1) * 32;
            const ushort8v* src = reinterpret_cast<const ushort8v*>(
                &Wz[(size_t)n * DM + k0 + cb]);
            ushort8v w0 = src[0], w1 = src[1], w2 = src[2], w3 = src[3];
            *reinterpret_cast<ushort8v*>(&Wl[n][cb + 0])  = w0;
            *reinterpret_cast<ushort8v*>(&Wl[n][cb + 8])  = w1;
            *reinterpret_cast<ushort8v*>(&Wl[n][cb + 16]) = w2;
            *reinterpret_cast<ushort8v*>(&Wl[n][cb + 24]) = w3;
        }
        __syncthreads();

#pragma unroll
        for (int c = 0; c < 2; ++c) {
            bf16x8 xf = *reinterpret_cast<const bf16x8*>(&Xl[wv * 16 + i16][c * 32 + g * 8]);
#pragma unroll
            for (int nt = 0; nt < 8; ++nt) {
                bf16x8 wf = *reinterpret_cast<const bf16x8*>(&Wl[nt * 16 + i16][c * 32 + g * 8]);
                acc[nt] = __builtin_amdgcn_mfma_f32_16x16x32_bf16(xf, wf, acc[nt], 0, 0, 0);
            }
        }
        __syncthreads();
    }

    if (z == 0) {
#pragma unroll
        for (int nt = 0; nt < 8; ++nt) {
            int n = nt * 16 + i16;
            float bb = bias[n];
#pragma unroll
            for (int r = 0; r < 4; ++r) {
                int mrow = m0 + wv * 16 + g * 4 + r;
                Qb[(size_t)mrow * DK + n] = f2bf((acc[nt][r] + bb) * QSCALE);
            }
        }
    } else if (z == 1) {
#pragma unroll
        for (int nt = 0; nt < 8; ++nt) {
            int n = nt * 16 + i16;
            float bb = bias[n];
#pragma unroll
            for (int r = 0; r < 4; ++r) {
                int mrow = m0 + wv * 16 + g * 4 + r;
                Kb[(size_t)mrow * DK + n] = f2bf(acc[nt][r] + bb);
            }
        }
    } else {
        const int b  = m0 / TT;
        const int t0 = (m0 % TT) + wv * 16 + g * 4;
#pragma unroll
        for (int nt = 0; nt < 8; ++nt) {
            int d = nt * 16 + i16;
            float bb = bias[d];
            ushort4v r;
#pragma unroll
            for (int e = 0; e < 4; ++e) r[e] = f2bf(acc[nt][e] + bb);
            *reinterpret_cast<ushort4v*>(&Vt[((size_t)b * DK + d) * TT + t0]) = r;
        }
    }
}

// ---------------------------------------------------------------------------
// LDS-staged flash attention, proportional split-K.
// Block = 8 waves; q-tile 128 rows (wave w owns rows w*16..+15).
// Per 64-key chunk: K (16KB) + V (16KB) staged reg->LDS, XOR-swizzled 16B
// slots; double-buffered; 1 barrier per chunk.
// FIX (r6): causal-mask fast path must compare chunk end against the wave's
// MIN row (qminw), not max row — waves 3/7 previously skipped masking on
// their diagonal chunk, admitting up to 15 future keys for rows qi<15.
// ---------------------------------------------------------------------------
__global__ __launch_bounds__(512, 2) void attn_kernel(
    const unsigned short* __restrict__ Qb, const unsigned short* __restrict__ Kb,
    const unsigned short* __restrict__ Vt,
    unsigned short* __restrict__ pO, float* __restrict__ pMS)
{
    __shared__ __align__(16) unsigned short lds_[2][16384];   // [buf][K 8192 | V 8192]

    const int t    = threadIdx.x;
    const int lane = t & 63;
    const int w    = t >> 6;
    const int qi   = lane & 15;
    const int g    = lane >> 4;

    // ---- decode block -> (batch, q-block, slice)
    const int bi    = blockIdx.x;
    const int batch = bi / NBLK;
    const int rr    = bi - batch * NBLK;
    int qbl = 0;
#pragma unroll
    for (int i = 1; i < 16; ++i) if (rr >= pfx_of(i)) qbl = i;
    const int slice = rr - (qbl == 0 ? 0 : 1 + (qbl * qbl - (qbl & 1)) / 4);
    const int S     = (qbl == 0) ? 1 : ((qbl + 1) >> 1);
    const int nch   = 2 * qbl + 2;            // 64-key chunks this q-block needs
    const int q0    = qbl * 128;              // batch-local first q row

    const unsigned short* __restrict__ Kbb = Kb + (size_t)batch * TT * DK;
    const unsigned short* __restrict__ Vtb = Vt + (size_t)batch * DK * TT;

    const int qrow  = q0 + w * 16 + qi;       // this lane's q (batch-local)
    const int qminw = q0 + w * 16;            // wave's min q row
    const int qmaxw = q0 + w * 16 + 15;       // wave's max q row

    bf16x8 qf[4];
#pragma unroll
    for (int c = 0; c < 4; ++c)
        qf[c] = *reinterpret_cast<const bf16x8*>(
            &Qb[((size_t)batch * TT + qrow) * DK + c * 32 + g * 8]);

    f32x4 accO[8];
#pragma unroll
    for (int dt = 0; dt < 8; ++dt) accO[dt] = (f32x4){0.f, 0.f, 0.f, 0.f};
    float m = -1e30f, s = 0.f;                // s lane-local, reduced at end

    // ---- staging helpers (wave w<4: K rows, w>=4: Vt rows), 4x16B per lane
    ushort8v sreg[4];
    const int kslot0 = (w & 3) * 256;

#define STAGE_ISSUE(c_)                                                         \
    {                                                                           \
        const int k0s = (c_) * 64;                                              \
        if (w < 4) {                                                            \
            _Pragma("unroll")                                                   \
            for (int i = 0; i < 4; ++i) {                                       \
                int slot = kslot0 + i * 64 + lane;                              \
                int row  = slot >> 4;                                           \
                int colg = (slot & 15) ^ (row & 15);                            \
                sreg[i] = *reinterpret_cast<const ushort8v*>(                   \
                    &Kbb[(size_t)(k0s + row) * DK + colg * 8]);                 \
            }                                                                   \
        } else {                                                                \
            _Pragma("unroll")                                                   \
            for (int i = 0; i < 4; ++i) {                                       \
                int slot = kslot0 + i * 64 + lane;                              \
                int row  = slot >> 3;                                           \
                int colg = (slot & 7) ^ (row & 7);                              \
                sreg[i] = *reinterpret_cast<const ushort8v*>(                   \
                    &Vtb[(size_t)row * TT + k0s + colg * 8]);                   \
            }                                                                   \
        }                                                                       \
    }

#define STAGE_WRITE(buf_)                                                       \
    {                                                                           \
        const int base = (w < 4) ? 0 : 8192;                                    \
        _Pragma("unroll")                                                       \
        for (int i = 0; i < 4; ++i) {                                           \
            int slot = kslot0 + i * 64 + lane;                                  \
            *reinterpret_cast<ushort8v*>(&lds_[buf_][base + slot * 8]) = sreg[i]; \
        }                                                                       \
    }

    // prologue: stage first chunk into buf 0
    STAGE_ISSUE(slice);
    STAGE_WRITE(0);
    __syncthreads();

    int buf = 0;
    for (int c = slice; c < nch; c += S) {
        const int cn = c + S;
        if (cn < nch) STAGE_ISSUE(cn);

        const int k0 = c * 64;
        if (k0 <= qmaxw) {
            // ---- QK^T (S^T): lane(qi,g) col=qi, rows k0+ks*16+g*4+r
            f32x4 accS[4];
#pragma unroll
            for (int ks = 0; ks < 4; ++ks) accS[ks] = (f32x4){0.f, 0.f, 0.f, 0.f};
#pragma unroll
            for (int cc = 0; cc < 4; ++cc) {
#pragma unroll
                for (int ks = 0; ks < 4; ++ks) {
                    bf16x8 kf = *reinterpret_cast<const bf16x8*>(
                        &lds_[buf][(ks * 16 + qi) * 128 + ((cc * 4 + g) ^ qi) * 8]);
                    accS[ks] = __builtin_amdgcn_mfma_f32_16x16x32_bf16(kf, qf[cc], accS[ks], 0, 0, 0);
                }
            }

            // ---- mask + local max (log2 domain already)
            // mask needed unless ALL 64 keys are <= the wave's MIN row
            float xmax = -1e30f;
            if (k0 + 63 > qminw) {
#pragma unroll
                for (int ks = 0; ks < 4; ++ks)
#pragma unroll
                    for (int r = 0; r < 4; ++r) {
                        int k = k0 + ks * 16 + g * 4 + r;
                        float v0 = (k <= qrow) ? accS[ks][r] : -1e30f;
                        accS[ks][r] = v0;
                        xmax = fmaxf(xmax, v0);
                    }
            } else {
#pragma unroll
                for (int ks = 0; ks < 4; ++ks)
#pragma unroll
                    for (int r = 0; r < 4; ++r) xmax = fmaxf(xmax, accS[ks][r]);
            }

            // ---- defer-max
            if (__any(xmax > m + 8.f)) {
                xmax = fmaxf(xmax, __shfl_xor(xmax, 16));
                xmax = fmaxf(xmax, __shfl_xor(xmax, 32));
                float mn   = fmaxf(m, xmax);
                float corr = __builtin_amdgcn_exp2f(m - mn);
                s *= corr;
#pragma unroll
                for (int dt = 0; dt < 8; ++dt)
#pragma unroll
                    for (int e = 0; e < 4; ++e) accO[dt][e] *= corr;
                m = mn;
            }

            // ---- exp2 + pack pairs: pk[ks*2+h] = (p(r=2h), p(r=2h+1))
            unsigned pk[8];
#pragma unroll
            for (int ks = 0; ks < 4; ++ks)
#pragma unroll
                for (int h = 0; h < 2; ++h) {
                    float plo = __builtin_amdgcn_exp2f(accS[ks][h * 2]     - m);
                    float phi = __builtin_amdgcn_exp2f(accS[ks][h * 2 + 1] - m);
                    s += plo + phi;
                    pk[ks * 2 + h] = (unsigned)f2bf(plo) | ((unsigned)f2bf(phi) << 16);
                }

            // ---- redistribute S^T -> PV B-fragments (16 shuffles)
            const int srcl0 = qi + 32 * (g & 1);
            bf16x8 pf[2];
#pragma unroll
            for (int c2 = 0; c2 < 2; ++c2) {
                union { unsigned u[4]; bf16x8 v; } pu;
#pragma unroll
                for (int w4 = 0; w4 < 4; ++w4) {
                    int srcl = srcl0 + 16 * (w4 >> 1);
                    int a = __shfl((int)pk[c2 * 4 + (w4 & 1)],     srcl);
                    int b = __shfl((int)pk[c2 * 4 + 2 + (w4 & 1)], srcl);
                    pu.u[w4] = (g & 2) ? (unsigned)b : (unsigned)a;
                }
                pf[c2] = pu.v;
            }

            // ---- PV: O^T += Vt-chunk . P
#pragma unroll
            for (int dt = 0; dt < 8; ++dt) {
#pragma unroll
                for (int c2 = 0; c2 < 2; ++c2) {
                    bf16x8 vf = *reinterpret_cast<const bf16x8*>(
                        &lds_[buf][8192 + (dt * 16 + qi) * 64 + ((c2 * 4 + g) ^ (qi & 7)) * 8]);
                    accO[dt] = __builtin_amdgcn_mfma_f32_16x16x32_bf16(vf, pf[c2], accO[dt], 0, 0, 0);
                }
            }
        }

        if (cn < nch) STAGE_WRITE(buf ^ 1);
        __syncthreads();
        buf ^= 1;
    }

    // ---- write partials
    float srow = s + __shfl_xor(s, 16);
    srow += __shfl_xor(srow, 32);

    const size_t prow = (size_t)bi * 128 + w * 16 + qi;
    if (g == 0) {
        pMS[prow * 2]     = m;
        pMS[prow * 2 + 1] = srow;
    }
#pragma unroll
    for (int dt = 0; dt < 8; ++dt) {
        ushort4v r;
#pragma unroll
        for (int e = 0; e < 4; ++e) r[e] = f2bf(accO[dt][e]);
        *reinterpret_cast<ushort4v*>(&pO[prow * DK + dt * 16 + g * 4]) = r;
    }
#undef STAGE_ISSUE
#undef STAGE_WRITE
}

// ---------------------------------------------------------------------------
// Combine split-K partials: O[r][d] = sum_s 2^(m_s-m*) accO_s / sum_s 2^(m_s-m*) s_s
// ---------------------------------------------------------------------------
__global__ __launch_bounds__(256) void attn_combine(
    const unsigned short* __restrict__ pO, const float* __restrict__ pMS,
    float* __restrict__ O)
{
    const int t  = threadIdx.x;
    const int r  = blockIdx.x * 8 + (t >> 5);     // global q row
    const int dq = (t & 31) * 4;

    const int batch = r >> 11;
    const int qbl   = (r >> 7) & 15;
    const int lr    = r & 127;
    const int S     = (qbl == 0) ? 1 : ((qbl + 1) >> 1);
    const int base  = batch * NBLK + (qbl == 0 ? 0 : 1 + (qbl * qbl - (qbl & 1)) / 4);

    float mstar = -1e30f;
    for (int ss = 0; ss < S; ++ss)
        mstar = fmaxf(mstar, pMS[((size_t)(base + ss) * 128 + lr) * 2]);

    float den = 0.f;
    float num[4] = {0.f, 0.f, 0.f, 0.f};
    for (int ss = 0; ss < S; ++ss) {
        const size_t pr = (size_t)(base + ss) * 128 + lr;
        float ms = pMS[pr * 2];
        float sv = pMS[pr * 2 + 1];
        float wgt = __builtin_amdgcn_exp2f(ms - mstar);
        den += wgt * sv;
        ushort4v ov = *reinterpret_cast<const ushort4v*>(&pO[pr * DK + dq]);
#pragma unroll
        for (int e = 0; e < 4; ++e) num[e] += wgt * bf2f(ov[e]);
    }

    const float inv = 1.f / den;
    float4 out;
    out.x = num[0] * inv; out.y = num[1] * inv;
    out.z = num[2] * inv; out.w = num[3] * inv;
    *reinterpret_cast<float4*>(&O[(size_t)r * DK + dq]) = out;
}

extern "C" void kernel_launch(void* const* d_in, const int* in_sizes, int n_in,
                              void* d_out, int out_size, void* d_ws, size_t ws_size,
                              hipStream_t stream) {
    const float* XQ  = (const float*)d_in[0];
    const float* XKV = (const float*)d_in[1];
    const float* Wq  = (const float*)d_in[2];
    const float* bq  = (const float*)d_in[3];
    const float* Wk  = (const float*)d_in[4];
    const float* bk  = (const float*)d_in[5];
    const float* Wv  = (const float*)d_in[6];
    const float* bv  = (const float*)d_in[7];

    unsigned short* Qb = (unsigned short*)d_ws;                 // 2 MB
    unsigned short* Kb = Qb + (size_t)BT * DK;                  // 2 MB
    unsigned short* Vt = Kb + (size_t)BT * DK;                  // 2 MB
    unsigned short* Wt = Vt + (size_t)BT * DK;                  // 0.75 MB
    float*          pMS = (float*)(Wt + (size_t)3 * DK * DM);   // 260*128*2 f32
    unsigned short* pO  = (unsigned short*)(pMS + (size_t)4 * NBLK * 128 * 2); // 8.5 MB

    wt_prep<<<dim3(16, 3), 256, 0, stream>>>(Wq, Wk, Wv, Wt);

    proj_mfma<<<dim3(BT / 64, 3), 256, 0, stream>>>(
        XQ, XKV, Wt, bq, bk, bv, Qb, Kb, Vt);

    attn_kernel<<<dim3(4 * NBLK), 512, 0, stream>>>(Qb, Kb, Vt, pO, pMS);

    attn_combine<<<dim3(BT / 8), 256, 0, stream>>>(pO, pMS, (float*)d_out);
}

// Round 7
// 61.659 us; speedup vs baseline: 25.5861x; 1.0682x over previous
//
#include <hip/hip_runtime.h>
#include <hip/hip_bf16.h>
#include <math.h>

#define BT 8192      // B*T rows total
#define TT 2048      // T
#define DM 1024      // d_model
#define DK 128       // dk == dv
#define NBLK 65      // split-K blocks per batch (sum of S over 16 q-blocks)

typedef __bf16 bf16x8 __attribute__((ext_vector_type(8)));
typedef float  f32x4  __attribute__((ext_vector_type(4)));
typedef unsigned short ushort4v __attribute__((ext_vector_type(4)));
typedef unsigned short ushort8v __attribute__((ext_vector_type(8)));

static __device__ __forceinline__ unsigned short f2bf(float x) {
    union { float f; unsigned u; } v; v.f = x;
    unsigned r = v.u + 0x7fffu + ((v.u >> 16) & 1u);   // RNE
    return (unsigned short)(r >> 16);
}
static __device__ __forceinline__ float bf2f(unsigned short u) {
    union { unsigned u; float f; } v; v.u = (unsigned)u << 16;
    return v.f;
}

// slices for q-block index q (0..15):  S = max(1, (q+1)>>1)   (sum = 65)
__host__ __device__ constexpr int slc_of(int q) { return (q == 0) ? 1 : ((q + 1) >> 1); }
__host__ __device__ constexpr int pfx_of(int q) { return (q == 0) ? 0 : 1 + (q * q - (q & 1)) / 4; }

// 1/sqrt(128) * log2(e): QK^T computed directly in log2 domain
#define QSCALE 0.1275312772629451f

// ---------------------------------------------------------------------------
// Prep: Wt[z][n][k] = bf16(W_z[k][n])
// ---------------------------------------------------------------------------
__global__ __launch_bounds__(256) void wt_prep(
    const float* __restrict__ Wq, const float* __restrict__ Wk,
    const float* __restrict__ Wv, unsigned short* __restrict__ Wt)
{
    const int z = blockIdx.y;
    const float* __restrict__ W = (z == 0) ? Wq : (z == 1 ? Wk : Wv);
    const int k0 = blockIdx.x * 64;

    __shared__ __align__(16) __bf16 T[128][72];
    const int t = threadIdx.x;

#pragma unroll
    for (int jj = 0; jj < 8; ++jj) {
        int c  = jj * 256 + t;
        int k  = c >> 5;
        int n4 = (c & 31) * 4;
        float4 f = *reinterpret_cast<const float4*>(&W[(size_t)(k0 + k) * DK + n4]);
        T[n4 + 0][k] = (__bf16)f.x;
        T[n4 + 1][k] = (__bf16)f.y;
        T[n4 + 2][k] = (__bf16)f.z;
        T[n4 + 3][k] = (__bf16)f.w;
    }
    __syncthreads();

    const int n  = t >> 1;
    const int cb = (t & 1) * 32;
#pragma unroll
    for (int jj = 0; jj < 4; ++jj) {
        *reinterpret_cast<ushort8v*>(&Wt[((size_t)z * DK + n) * DM + k0 + cb + jj * 8]) =
            *reinterpret_cast<const ushort8v*>(&T[n][cb + jj * 8]);
    }
}

// ---------------------------------------------------------------------------
// Projection via MFMA, v2 (r7):
//  - X (A-operand) is wave-private -> loaded global->reg->bf16 directly,
//    no LDS staging at all for X.
//  - W double-buffered in LDS, reg-prefetched 1 iter ahead (T14 split),
//    ONE barrier per K-iter, unroll-by-2 so buffer indices are static.
// Tile 64x128 per block, BK=64, 4 waves (wave = 16 rows x 128 cols).
// ---------------------------------------------------------------------------
__global__ __launch_bounds__(256, 4) void proj_mfma(
    const float* __restrict__ XQ, const float* __restrict__ XKV,
    const unsigned short* __restrict__ Wt,
    const float* __restrict__ bq, const float* __restrict__ bk,
    const float* __restrict__ bv,
    unsigned short* __restrict__ Qb, unsigned short* __restrict__ Kb,
    unsigned short* __restrict__ Vt)
{
    const int z = blockIdx.y;
    const float* __restrict__ X    = (z == 0) ? XQ : XKV;
    const float* __restrict__ bias = (z == 0) ? bq : (z == 1 ? bk : bv);
    const unsigned short* __restrict__ Wz = Wt + (size_t)z * DK * DM;

    __shared__ __align__(16) __bf16 Wl[2][128][72];

    const int t    = threadIdx.x;
    const int lane = t & 63;
    const int wv   = t >> 6;
    const int i16  = lane & 15;
    const int g    = lane >> 4;
    const int m0   = blockIdx.x * 64;

    // this lane's X row (A-fragment source) and W staging row
    const float* __restrict__ Xrow =
        X + (size_t)(m0 + wv * 16 + i16) * DM + g * 8;
    const unsigned short* __restrict__ Wrow =
        Wz + (size_t)(t >> 1) * DM + (t & 1) * 32;

    f32x4 acc[8];
#pragma unroll
    for (int nt = 0; nt < 8; ++nt) acc[nt] = (f32x4){0.f, 0.f, 0.f, 0.f};

    float4   xa[4], xb[4];    // X fragments (even / odd iters)
    ushort8v wr_[4];          // W stage regs (next iter)

#define LOADX(xr_, k0_)                                                        \
    {                                                                          \
        _Pragma("unroll")                                                      \
        for (int c = 0; c < 2; ++c)                                            \
            _Pragma("unroll")                                                  \
            for (int h = 0; h < 2; ++h)                                        \
                xr_[c * 2 + h] = *reinterpret_cast<const float4*>(             \
                    &Xrow[(k0_) + c * 32 + h * 4]);                            \
    }
#define LOADW(k0_)                                                             \
    {                                                                          \
        _Pragma("unroll")                                                      \
        for (int i = 0; i < 4; ++i)                                            \
            wr_[i] = *reinterpret_cast<const ushort8v*>(&Wrow[(k0_) + i * 8]); \
    }
#define WRITEW(buf_)                                                           \
    {                                                                          \
        _Pragma("unroll")                                                      \
        for (int i = 0; i < 4; ++i)                                            \
            *reinterpret_cast<ushort8v*>(                                      \
                &Wl[buf_][t >> 1][(t & 1) * 32 + i * 8]) = wr_[i];             \
    }
#define COMPUTE(xr_, buf_)                                                     \
    {                                                                          \
        _Pragma("unroll")                                                      \
        for (int c = 0; c < 2; ++c) {                                          \
            union { __bf16 b[8]; bf16x8 v; } u;                                \
            u.b[0] = (__bf16)xr_[c * 2].x;  u.b[1] = (__bf16)xr_[c * 2].y;     \
            u.b[2] = (__bf16)xr_[c * 2].z;  u.b[3] = (__bf16)xr_[c * 2].w;     \
            u.b[4] = (__bf16)xr_[c * 2 + 1].x; u.b[5] = (__bf16)xr_[c * 2 + 1].y; \
            u.b[6] = (__bf16)xr_[c * 2 + 1].z; u.b[7] = (__bf16)xr_[c * 2 + 1].w; \
            _Pragma("unroll")                                                  \
            for (int nt = 0; nt < 8; ++nt) {                                   \
                bf16x8 wf = *reinterpret_cast<const bf16x8*>(                  \
                    &Wl[buf_][nt * 16 + i16][c * 32 + g * 8]);                 \
                acc[nt] = __builtin_amdgcn_mfma_f32_16x16x32_bf16(u.v, wf, acc[nt], 0, 0, 0); \
            }                                                                  \
        }                                                                      \
    }

    // prologue: chunk 0 into buf0; prefetch chunk 1
    LOADX(xa, 0);
    LOADW(0);
    WRITEW(0);
    __syncthreads();
    LOADW(64);
    LOADX(xb, 64);

#pragma unroll
    for (int t2 = 0; t2 < 16; t2 += 2) {
        // even chunk t2 from buf0; stage chunk t2+1 -> buf1
        COMPUTE(xa, 0);
        WRITEW(1);
        __syncthreads();
        if (t2 + 2 < 16) { LOADW((t2 + 2) * 64); LOADX(xa, (t2 + 2) * 64); }
        // odd chunk t2+1 from buf1; stage chunk t2+2 -> buf0
        COMPUTE(xb, 1);
        if (t2 + 3 < 16) WRITEW(0);
        __syncthreads();
        if (t2 + 3 < 16) { LOADW((t2 + 3) * 64); LOADX(xb, (t2 + 3) * 64); }
    }
#undef LOADX
#undef LOADW
#undef WRITEW
#undef COMPUTE

    if (z == 0) {
#pragma unroll
        for (int nt = 0; nt < 8; ++nt) {
            int n = nt * 16 + i16;
            float bb = bias[n];
#pragma unroll
            for (int r = 0; r < 4; ++r) {
                int mrow = m0 + wv * 16 + g * 4 + r;
                Qb[(size_t)mrow * DK + n] = f2bf((acc[nt][r] + bb) * QSCALE);
            }
        }
    } else if (z == 1) {
#pragma unroll
        for (int nt = 0; nt < 8; ++nt) {
            int n = nt * 16 + i16;
            float bb = bias[n];
#pragma unroll
            for (int r = 0; r < 4; ++r) {
                int mrow = m0 + wv * 16 + g * 4 + r;
                Kb[(size_t)mrow * DK + n] = f2bf(acc[nt][r] + bb);
            }
        }
    } else {
        const int b  = m0 / TT;
        const int t0 = (m0 % TT) + wv * 16 + g * 4;
#pragma unroll
        for (int nt = 0; nt < 8; ++nt) {
            int d = nt * 16 + i16;
            float bb = bias[d];
            ushort4v r;
#pragma unroll
            for (int e = 0; e < 4; ++e) r[e] = f2bf(acc[nt][e] + bb);
            *reinterpret_cast<ushort4v*>(&Vt[((size_t)b * DK + d) * TT + t0]) = r;
        }
    }
}

// ---------------------------------------------------------------------------
// LDS-staged flash attention, proportional split-K (unchanged from r6).
// ---------------------------------------------------------------------------
__global__ __launch_bounds__(512, 2) void attn_kernel(
    const unsigned short* __restrict__ Qb, const unsigned short* __restrict__ Kb,
    const unsigned short* __restrict__ Vt,
    unsigned short* __restrict__ pO, float* __restrict__ pMS)
{
    __shared__ __align__(16) unsigned short lds_[2][16384];   // [buf][K 8192 | V 8192]

    const int t    = threadIdx.x;
    const int lane = t & 63;
    const int w    = t >> 6;
    const int qi   = lane & 15;
    const int g    = lane >> 4;

    // ---- decode block -> (batch, q-block, slice)
    const int bi    = blockIdx.x;
    const int batch = bi / NBLK;
    const int rr    = bi - batch * NBLK;
    int qbl = 0;
#pragma unroll
    for (int i = 1; i < 16; ++i) if (rr >= pfx_of(i)) qbl = i;
    const int slice = rr - (qbl == 0 ? 0 : 1 + (qbl * qbl - (qbl & 1)) / 4);
    const int S     = (qbl == 0) ? 1 : ((qbl + 1) >> 1);
    const int nch   = 2 * qbl + 2;            // 64-key chunks this q-block needs
    const int q0    = qbl * 128;              // batch-local first q row

    const unsigned short* __restrict__ Kbb = Kb + (size_t)batch * TT * DK;
    const unsigned short* __restrict__ Vtb = Vt + (size_t)batch * DK * TT;

    const int qrow  = q0 + w * 16 + qi;       // this lane's q (batch-local)
    const int qminw = q0 + w * 16;            // wave's min q row
    const int qmaxw = q0 + w * 16 + 15;       // wave's max q row

    bf16x8 qf[4];
#pragma unroll
    for (int c = 0; c < 4; ++c)
        qf[c] = *reinterpret_cast<const bf16x8*>(
            &Qb[((size_t)batch * TT + qrow) * DK + c * 32 + g * 8]);

    f32x4 accO[8];
#pragma unroll
    for (int dt = 0; dt < 8; ++dt) accO[dt] = (f32x4){0.f, 0.f, 0.f, 0.f};
    float m = -1e30f, s = 0.f;                // s lane-local, reduced at end

    // ---- staging helpers (wave w<4: K rows, w>=4: Vt rows), 4x16B per lane
    ushort8v sreg[4];
    const int kslot0 = (w & 3) * 256;

#define STAGE_ISSUE(c_)                                                         \
    {                                                                           \
        const int k0s = (c_) * 64;                                              \
        if (w < 4) {                                                            \
            _Pragma("unroll")                                                   \
            for (int i = 0; i < 4; ++i) {                                       \
                int slot = kslot0 + i * 64 + lane;                              \
                int row  = slot >> 4;                                           \
                int colg = (slot & 15) ^ (row & 15);                            \
                sreg[i] = *reinterpret_cast<const ushort8v*>(                   \
                    &Kbb[(size_t)(k0s + row) * DK + colg * 8]);                 \
            }                                                                   \
        } else {                                                                \
            _Pragma("unroll")                                                   \
            for (int i = 0; i < 4; ++i) {                                       \
                int slot = kslot0 + i * 64 + lane;                              \
                int row  = slot >> 3;                                           \
                int colg = (slot & 7) ^ (row & 7);                              \
                sreg[i] = *reinterpret_cast<const ushort8v*>(                   \
                    &Vtb[(size_t)row * TT + k0s + colg * 8]);                   \
            }                                                                   \
        }                                                                       \
    }

#define STAGE_WRITE(buf_)                                                       \
    {                                                                           \
        const int base = (w < 4) ? 0 : 8192;                                    \
        _Pragma("unroll")                                                       \
        for (int i = 0; i < 4; ++i) {                                           \
            int slot = kslot0 + i * 64 + lane;                                  \
            *reinterpret_cast<ushort8v*>(&lds_[buf_][base + slot * 8]) = sreg[i]; \
        }                                                                       \
    }

    // prologue: stage first chunk into buf 0
    STAGE_ISSUE(slice);
    STAGE_WRITE(0);
    __syncthreads();

    int buf = 0;
    for (int c = slice; c < nch; c += S) {
        const int cn = c + S;
        if (cn < nch) STAGE_ISSUE(cn);

        const int k0 = c * 64;
        if (k0 <= qmaxw) {
            // ---- QK^T (S^T): lane(qi,g) col=qi, rows k0+ks*16+g*4+r
            f32x4 accS[4];
#pragma unroll
            for (int ks = 0; ks < 4; ++ks) accS[ks] = (f32x4){0.f, 0.f, 0.f, 0.f};
#pragma unroll
            for (int cc = 0; cc < 4; ++cc) {
#pragma unroll
                for (int ks = 0; ks < 4; ++ks) {
                    bf16x8 kf = *reinterpret_cast<const bf16x8*>(
                        &lds_[buf][(ks * 16 + qi) * 128 + ((cc * 4 + g) ^ qi) * 8]);
                    accS[ks] = __builtin_amdgcn_mfma_f32_16x16x32_bf16(kf, qf[cc], accS[ks], 0, 0, 0);
                }
            }

            // ---- mask + local max (log2 domain already)
            // mask needed unless ALL 64 keys are <= the wave's MIN row
            float xmax = -1e30f;
            if (k0 + 63 > qminw) {
#pragma unroll
                for (int ks = 0; ks < 4; ++ks)
#pragma unroll
                    for (int r = 0; r < 4; ++r) {
                        int k = k0 + ks * 16 + g * 4 + r;
                        float v0 = (k <= qrow) ? accS[ks][r] : -1e30f;
                        accS[ks][r] = v0;
                        xmax = fmaxf(xmax, v0);
                    }
            } else {
#pragma unroll
                for (int ks = 0; ks < 4; ++ks)
#pragma unroll
                    for (int r = 0; r < 4; ++r) xmax = fmaxf(xmax, accS[ks][r]);
            }

            // ---- defer-max
            if (__any(xmax > m + 8.f)) {
                xmax = fmaxf(xmax, __shfl_xor(xmax, 16));
                xmax = fmaxf(xmax, __shfl_xor(xmax, 32));
                float mn   = fmaxf(m, xmax);
                float corr = __builtin_amdgcn_exp2f(m - mn);
                s *= corr;
#pragma unroll
                for (int dt = 0; dt < 8; ++dt)
#pragma unroll
                    for (int e = 0; e < 4; ++e) accO[dt][e] *= corr;
                m = mn;
            }

            // ---- exp2 + pack pairs: pk[ks*2+h] = (p(r=2h), p(r=2h+1))
            unsigned pk[8];
#pragma unroll
            for (int ks = 0; ks < 4; ++ks)
#pragma unroll
                for (int h = 0; h < 2; ++h) {
                    float plo = __builtin_amdgcn_exp2f(accS[ks][h * 2]     - m);
                    float phi = __builtin_amdgcn_exp2f(accS[ks][h * 2 + 1] - m);
                    s += plo + phi;
                    pk[ks * 2 + h] = (unsigned)f2bf(plo) | ((unsigned)f2bf(phi) << 16);
                }

            // ---- redistribute S^T -> PV B-fragments (16 shuffles)
            const int srcl0 = qi + 32 * (g & 1);
            bf16x8 pf[2];
#pragma unroll
            for (int c2 = 0; c2 < 2; ++c2) {
                union { unsigned u[4]; bf16x8 v; } pu;
#pragma unroll
                for (int w4 = 0; w4 < 4; ++w4) {
                    int srcl = srcl0 + 16 * (w4 >> 1);
                    int a = __shfl((int)pk[c2 * 4 + (w4 & 1)],     srcl);
                    int b = __shfl((int)pk[c2 * 4 + 2 + (w4 & 1)], srcl);
                    pu.u[w4] = (g & 2) ? (unsigned)b : (unsigned)a;
                }
                pf[c2] = pu.v;
            }

            // ---- PV: O^T += Vt-chunk . P
#pragma unroll
            for (int dt = 0; dt < 8; ++dt) {
#pragma unroll
                for (int c2 = 0; c2 < 2; ++c2) {
                    bf16x8 vf = *reinterpret_cast<const bf16x8*>(
                        &lds_[buf][8192 + (dt * 16 + qi) * 64 + ((c2 * 4 + g) ^ (qi & 7)) * 8]);
                    accO[dt] = __builtin_amdgcn_mfma_f32_16x16x32_bf16(vf, pf[c2], accO[dt], 0, 0, 0);
                }
            }
        }

        if (cn < nch) STAGE_WRITE(buf ^ 1);
        __syncthreads();
        buf ^= 1;
    }

    // ---- write partials
    float srow = s + __shfl_xor(s, 16);
    srow += __shfl_xor(srow, 32);

    const size_t prow = (size_t)bi * 128 + w * 16 + qi;
    if (g == 0) {
        pMS[prow * 2]     = m;
        pMS[prow * 2 + 1] = srow;
    }
#pragma unroll
    for (int dt = 0; dt < 8; ++dt) {
        ushort4v r;
#pragma unroll
        for (int e = 0; e < 4; ++e) r[e] = f2bf(accO[dt][e]);
        *reinterpret_cast<ushort4v*>(&pO[prow * DK + dt * 16 + g * 4]) = r;
    }
#undef STAGE_ISSUE
#undef STAGE_WRITE
}

// ---------------------------------------------------------------------------
// Combine split-K partials (unchanged from r6).
// ---------------------------------------------------------------------------
__global__ __launch_bounds__(256) void attn_combine(
    const unsigned short* __restrict__ pO, const float* __restrict__ pMS,
    float* __restrict__ O)
{
    const int t  = threadIdx.x;
    const int r  = blockIdx.x * 8 + (t >> 5);     // global q row
    const int dq = (t & 31) * 4;

    const int batch = r >> 11;
    const int qbl   = (r >> 7) & 15;
    const int lr    = r & 127;
    const int S     = (qbl == 0) ? 1 : ((qbl + 1) >> 1);
    const int base  = batch * NBLK + (qbl == 0 ? 0 : 1 + (qbl * qbl - (qbl & 1)) / 4);

    float mstar = -1e30f;
    for (int ss = 0; ss < S; ++ss)
        mstar = fmaxf(mstar, pMS[((size_t)(base + ss) * 128 + lr) * 2]);

    float den = 0.f;
    float num[4] = {0.f, 0.f, 0.f, 0.f};
    for (int ss = 0; ss < S; ++ss) {
        const size_t pr = (size_t)(base + ss) * 128 + lr;
        float ms = pMS[pr * 2];
        float sv = pMS[pr * 2 + 1];
        float wgt = __builtin_amdgcn_exp2f(ms - mstar);
        den += wgt * sv;
        ushort4v ov = *reinterpret_cast<const ushort4v*>(&pO[pr * DK + dq]);
#pragma unroll
        for (int e = 0; e < 4; ++e) num[e] += wgt * bf2f(ov[e]);
    }

    const float inv = 1.f / den;
    float4 out;
    out.x = num[0] * inv; out.y = num[1] * inv;
    out.z = num[2] * inv; out.w = num[3] * inv;
    *reinterpret_cast<float4*>(&O[(size_t)r * DK + dq]) = out;
}

extern "C" void kernel_launch(void* const* d_in, const int* in_sizes, int n_in,
                              void* d_out, int out_size, void* d_ws, size_t ws_size,
                              hipStream_t stream) {
    const float* XQ  = (const float*)d_in[0];
    const float* XKV = (const float*)d_in[1];
    const float* Wq  = (const float*)d_in[2];
    const float* bq  = (const float*)d_in[3];
    const float* Wk  = (const float*)d_in[4];
    const float* bk  = (const float*)d_in[5];
    const float* Wv  = (const float*)d_in[6];
    const float* bv  = (const float*)d_in[7];

    unsigned short* Qb = (unsigned short*)d_ws;                 // 2 MB
    unsigned short* Kb = Qb + (size_t)BT * DK;                  // 2 MB
    unsigned short* Vt = Kb + (size_t)BT * DK;                  // 2 MB
    unsigned short* Wt = Vt + (size_t)BT * DK;                  // 0.75 MB
    float*          pMS = (float*)(Wt + (size_t)3 * DK * DM);   // 260*128*2 f32
    unsigned short* pO  = (unsigned short*)(pMS + (size_t)4 * NBLK * 128 * 2); // 8.5 MB

    wt_prep<<<dim3(16, 3), 256, 0, stream>>>(Wq, Wk, Wv, Wt);

    proj_mfma<<<dim3(BT / 64, 3), 256, 0, stream>>>(
        XQ, XKV, Wt, bq, bk, bv, Qb, Kb, Vt);

    attn_kernel<<<dim3(4 * NBLK), 512, 0, stream>>>(Qb, Kb, Vt, pO, pMS);

    attn_combine<<<dim3(BT / 8), 256, 0, stream>>>(pO, pMS, (float*)d_out);
}